// Round 7
// baseline (320.639 us; speedup 1.0000x reference)
//
#include <hip/hip_runtime.h>
#include <hip/hip_bf16.h>

// ---------------------------------------------------------------------------
// LucasKANLayer fused: y[b,o] = sum_i sum_d L_d(tanh(x[b,i])) * C[i,o,d]
// R7: SINGLE-WAVE workgroups (64 thr) -> wave-private LDS, ZERO barriers.
// Sync is s_waitcnt vmcnt(18): wait only the previous buffer's 18 staging
// loads; the 18 prefetch loads stay in flight (AITER-style, impossible with
// __syncthreads). Wave tile 128m x 128n (acc 256 VGPR), 64 indep MFMAs per
// k2 -> single wave saturates its SIMD matrix pipe. Grid (8,64,2) = 1024
// one-wave blocks = 1 wave/SIMD; LDS 36 KB x 4 blocks/CU = 144 KB.
// ---------------------------------------------------------------------------

typedef __attribute__((ext_vector_type(8)))  short  short8;    // bf16x8 MFMA frag
typedef __attribute__((ext_vector_type(4)))  unsigned short ushort4v;
typedef __attribute__((ext_vector_type(8)))  unsigned short ushort8;
typedef __attribute__((ext_vector_type(4)))  float  float4v;
typedef __attribute__((ext_vector_type(4)))  unsigned int uint4v;

#define M_DIM 8192
#define I_DIM 1024
#define O_DIM 1024
#define K_DIM 8192   // I_DIM * 8
#define WM 128       // wave tile m
#define WN 128       // wave tile n
#define BK 64        // 8 i-values per K-step
#define KSPLIT 2
#define KHALF (K_DIM / KSPLIT)
#define NSTEP (KHALF / BK)   // 64

// s_waitcnt imm: vmcnt low4 [3:0], high2 [15:14]; expcnt [6:4]; lgkmcnt [11:8]
#define WAITCNT_VM18  0x4F72   // vmcnt(18), lgkm/exp free
#define WAITCNT_VM0   0x0F70   // vmcnt(0),  lgkm/exp free
#define WAITCNT_LGKM0 0xC07F   // lgkmcnt(0), vm/exp free (WAR guard pre-stage)

// round-to-nearest-even fp32 -> bf16 bits (prep kernel)
__device__ __forceinline__ unsigned short f2bf(float f) {
    unsigned int u = __float_as_uint(f);
    u += 0x7FFFu + ((u >> 16) & 1u);
    return (unsigned short)(u >> 16);
}

// ---- zero out (harness poisons d_out with 0xAA; atomics need 0) ----
__global__ __launch_bounds__(256) void zero_kernel(float* __restrict__ p) {
    int idx = (blockIdx.x * 256 + threadIdx.x) * 4;
    const float4v z = {0.f, 0.f, 0.f, 0.f};
    *(float4v*)(p + idx) = z;
}

// ---- fused prep ----
// T[b][group g][slot]: slot 2p = t(i=g*8+p), slot 2p+1 = t(i=g*8+p+4)
// so a b32 LDS read at u16-offset quad*2 gives {lo=t(quad), hi=t(quad+4)}.
// Bt[o][i*8+d] = bf16(coeffs[i][o][d]).
__global__ __launch_bounds__(256) void prep_kernel(const float* __restrict__ x,
                                                   const float* __restrict__ c,
                                                   unsigned short* __restrict__ T,
                                                   unsigned short* __restrict__ Bt) {
    int bid = blockIdx.x;
    const int tPart = (M_DIM * I_DIM) / (8 * 256);   // 4096 blocks, 8 elems/thread
    if (bid < tPart) {
        int idx = (bid * 256 + threadIdx.x) * 8;
        float4v v0 = *(const float4v*)(x + idx);
        float4v v1 = *(const float4v*)(x + idx + 4);
        unsigned short t[8];
        t[0] = f2bf(tanhf(v0[0])); t[1] = f2bf(tanhf(v0[1]));
        t[2] = f2bf(tanhf(v0[2])); t[3] = f2bf(tanhf(v0[3]));
        t[4] = f2bf(tanhf(v1[0])); t[5] = f2bf(tanhf(v1[1]));
        t[6] = f2bf(tanhf(v1[2])); t[7] = f2bf(tanhf(v1[3]));
        ushort8 o;
        #pragma unroll
        for (int p = 0; p < 4; ++p) { o[2 * p] = t[p]; o[2 * p + 1] = t[p + 4]; }
        *(ushort8*)(T + idx) = o;
    } else {
        int idx = (bid - tPart) * 256 + threadIdx.x; // one (i,o) per thread
        int i = idx >> 10;
        int o = idx & 1023;
        const float* src = c + (size_t)i * 8192 + o * 8;
        float4v lo = *(const float4v*)(src);
        float4v hi = *(const float4v*)(src + 4);
        ushort8 v;
        v[0] = f2bf(lo[0]); v[1] = f2bf(lo[1]); v[2] = f2bf(lo[2]); v[3] = f2bf(lo[3]);
        v[4] = f2bf(hi[0]); v[5] = f2bf(hi[1]); v[6] = f2bf(hi[2]); v[7] = f2bf(hi[3]);
        *(ushort8*)(Bt + (size_t)o * K_DIM + i * 8) = v;
    }
}

// Lucas A-fragment {2, t, L2..L7} packed bf16x8 from bf16 t-bits tb (low 16).
__device__ __forceinline__ short8 lucas_frag(unsigned int tb) {
    const float t = __uint_as_float(tb << 16);
    const float L2v = fmaf(t, t, 2.0f);
    const float L3v = fmaf(t, L2v, t);
    const float L4v = fmaf(t, L3v, L2v);
    const float L5v = fmaf(t, L4v, L3v);
    const float L6v = fmaf(t, L5v, L4v);
    const float L7v = fmaf(t, L6v, L5v);
    union { uint4v u; short8 s; } r;
#if __has_builtin(__builtin_amdgcn_cvt_pk_bf16_f32)
    {
        auto p0 = __builtin_amdgcn_cvt_pk_bf16_f32(2.0f, t);
        auto p1 = __builtin_amdgcn_cvt_pk_bf16_f32(L2v, L3v);
        auto p2 = __builtin_amdgcn_cvt_pk_bf16_f32(L4v, L5v);
        auto p3 = __builtin_amdgcn_cvt_pk_bf16_f32(L6v, L7v);
        __builtin_memcpy(&r.u[0], &p0, 4);
        __builtin_memcpy(&r.u[1], &p1, 4);
        __builtin_memcpy(&r.u[2], &p2, 4);
        __builtin_memcpy(&r.u[3], &p3, 4);
    }
#else
    {
        r.u[0] = 0x4000u | (tb << 16);
        r.u[1] = __builtin_amdgcn_perm(__float_as_uint(L3v), __float_as_uint(L2v), 0x07060302);
        r.u[2] = __builtin_amdgcn_perm(__float_as_uint(L5v), __float_as_uint(L4v), 0x07060302);
        r.u[3] = __builtin_amdgcn_perm(__float_as_uint(L7v), __float_as_uint(L6v), 0x07060302);
    }
#endif
    return r.s;
}

// ---- single-wave GEMM: out[m][n] += sum_{k half} A[m][k] * Bt[n][k] ----
__global__ __launch_bounds__(64, 1) void gemm_kernel(const unsigned short* __restrict__ T,
                                                     const unsigned short* __restrict__ Bt,
                                                     float* __restrict__ out) {
    __shared__ unsigned short Bs[2][WN * BK];   // 32 KB, XOR-swizzled, dbuf
    __shared__ unsigned short Ts[2][WM * 8];    // 4 KB, dbuf (permuted 8-groups)

    const int lane = threadIdx.x;               // one wave per block
    const int n0 = blockIdx.x * WN;             // x = n-panel (8): XCD = linear%8
    const int m0 = blockIdx.y * WM;             // y = m (64)
    const int k0 = blockIdx.z * KHALF;          // z = K half (2)

    const int l16  = lane & 15;
    const int quad = lane >> 4;
    const int srow = lane >> 3;                 // 0..7
    const int il   = lane & 7;
    const int gchunk = il ^ srow;               // XOR-swizzled global 16B chunk

    float4v acc[8][8];
    const float4v zero = {0.f, 0.f, 0.f, 0.f};
    #pragma unroll
    for (int a = 0; a < 8; ++a)
        #pragma unroll
        for (int b = 0; b < 8; ++b) acc[a][b] = zero;

    // stage one K-step (18 global_load_lds: 16 for B, 2 for T)
    auto stage = [&](int buf, int kt) {
        #pragma unroll
        for (int r = 0; r < 16; ++r) {
            const unsigned short* gB = Bt + (size_t)(n0 + r * 8 + srow) * K_DIM + kt + gchunk * 8;
            __builtin_amdgcn_global_load_lds(
                (const __attribute__((address_space(1))) unsigned int*)gB,
                (__attribute__((address_space(3))) unsigned int*)&Bs[buf][r * 8 * BK], 16, 0, 0);
        }
        #pragma unroll
        for (int j = 0; j < 2; ++j) {
            const unsigned short* gT = T + (size_t)(m0 + j * 64 + lane) * I_DIM + kt / 8;
            __builtin_amdgcn_global_load_lds(
                (const __attribute__((address_space(1))) unsigned int*)gT,
                (__attribute__((address_space(3))) unsigned int*)&Ts[buf][j * 64 * 8], 16, 0, 0);
        }
    };

    stage(0, k0);

    for (int s = 0; s < NSTEP; ++s) {
        const int cur = s & 1;
        if (s + 1 < NSTEP) {
            __builtin_amdgcn_s_waitcnt(WAITCNT_LGKM0);  // WAR guard: prior reads done
            stage(cur ^ 1, k0 + (s + 1) * BK);
            __builtin_amdgcn_s_waitcnt(WAITCNT_VM18);   // cur's 18 done; 18 stay in flight
        } else {
            __builtin_amdgcn_s_waitcnt(WAITCNT_VM0);    // last step: drain
        }

        // t-words: one b32 per m-tile {lo=t(quad)->k2=0, hi=t(quad+4)->k2=1}
        unsigned int tw[8];
        #pragma unroll
        for (int tt = 0; tt < 8; ++tt)
            tw[tt] = *(const unsigned int*)&Ts[cur][(tt * 16 + l16) * 8 + quad * 2];

        #pragma unroll
        for (int k2 = 0; k2 < 2; ++k2) {
            short8 bfr[8];
            #pragma unroll
            for (int tn = 0; tn < 8; ++tn) {
                const int brow = tn * 16 + l16;
                bfr[tn] = *(const short8*)&Bs[cur][brow * BK + (((k2 * 4 + quad) ^ (l16 & 7)) * 8)];
            }
            #pragma unroll
            for (int tt = 0; tt < 8; ++tt) {
                const short8 af = lucas_frag(k2 ? (tw[tt] >> 16) : (tw[tt] & 0xffffu));
                #pragma unroll
                for (int tn = 0; tn < 8; ++tn)
                    acc[tt][tn] = __builtin_amdgcn_mfma_f32_16x16x32_bf16(
                        af, bfr[tn], acc[tt][tn], 0, 0, 0);
            }
        }
    }

    // epilogue: atomic accumulate (KSPLIT writers). D[row=(lane>>4)*4+r][col=lane&15]
    #pragma unroll
    for (int tt = 0; tt < 8; ++tt) {
        #pragma unroll
        for (int tn = 0; tn < 8; ++tn) {
            const int col = n0 + tn * 16 + l16;
            #pragma unroll
            for (int r = 0; r < 4; ++r) {
                const int row = m0 + tt * 16 + quad * 4 + r;
                atomicAdd(&out[(size_t)row * O_DIM + col], acc[tt][tn][r]);
            }
        }
    }
}

// ---- fallback (tiny workspace): direct fp32 ----
__global__ __launch_bounds__(256) void naive_kernel(const float* __restrict__ x,
                                                    const float* __restrict__ c,
                                                    float* __restrict__ out) {
    int idx = blockIdx.x * 256 + threadIdx.x;   // one (b,o)
    int b = idx >> 10;
    int o = idx & 1023;
    const float* xb = x + (size_t)b * I_DIM;
    float acc = 0.f;
    for (int i = 0; i < I_DIM; ++i) {
        float t = tanhf(xb[i]);
        float L[8];
        L[0] = 2.0f; L[1] = t;
        #pragma unroll
        for (int d = 2; d < 8; ++d) L[d] = t * L[d - 1] + L[d - 2];
        const float* cc = c + (size_t)i * 8192 + o * 8;
        #pragma unroll
        for (int d = 0; d < 8; ++d) acc += L[d] * cc[d];
    }
    out[idx] = acc;
}

extern "C" void kernel_launch(void* const* d_in, const int* in_sizes, int n_in,
                              void* d_out, int out_size, void* d_ws, size_t ws_size,
                              hipStream_t stream) {
    const float* x      = (const float*)d_in[0];
    const float* coeffs = (const float*)d_in[1];
    float* out = (float*)d_out;

    const size_t btBytes = (size_t)O_DIM * K_DIM * sizeof(unsigned short);   // 16 MiB
    const size_t tBytes  = (size_t)M_DIM * I_DIM * sizeof(unsigned short);   // 16 MiB

    if (ws_size >= btBytes + tBytes) {
        unsigned short* Bt = (unsigned short*)d_ws;
        unsigned short* T  = (unsigned short*)((char*)d_ws + btBytes);

        zero_kernel<<<(M_DIM * O_DIM) / (4 * 256), 256, 0, stream>>>(out);

        const int tBlocks = (M_DIM * I_DIM) / (8 * 256);   // 4096
        const int bBlocks = (I_DIM * O_DIM) / 256;          // 4096
        prep_kernel<<<tBlocks + bBlocks, 256, 0, stream>>>(x, coeffs, T, Bt);

        dim3 grid(O_DIM / WN, M_DIM / WM, KSPLIT);   // (8, 64, 2): XCD = x
        gemm_kernel<<<grid, 64, 0, stream>>>(T, Bt, out);
    } else {
        naive_kernel<<<(M_DIM * O_DIM) / 256, 256, 0, stream>>>(x, coeffs, out);
    }
}

// Round 8
// 259.887 us; speedup vs baseline: 1.2338x; 1.2338x over previous
//
#include <hip/hip_runtime.h>
#include <hip/hip_bf16.h>

// ---------------------------------------------------------------------------
// LucasKANLayer fused: y[b,o] = sum_i sum_d L_d(tanh(x[b,i])) * C[i,o,d]
// R8 = R6 structure (4-wave block, 1 barrier/step, global_load_lds dbuf,
// XOR-swizzled LDS, XCD-pinned B-panels) but:
//  - mfma_f32_32x32x16_bf16 (peak shape, 2495 TF ubench vs 2075): A-frag is
//    still 8 consecutive k = the 8 Lucas values of ONE t -> register expansion
//    unchanged; half the MFMA instructions, 17% less matrix-pipe per FLOP.
//  - block 256m x 128n (wave 64m x 128n, acc 2x4x16=128 VGPR): B-staging
//    bytes/FLOP halved (R6 was at the per-CU L2 BW ceiling), expansion
//    VALU/FLOP halved.
//  - grid (8 n-panels, 32 m, 2 kz) = 512 blocks = 2/CU; XCD=linear%8=n-panel.
//  - T permuted [i0,i2,i4,i6,i1,i3,i5,i7]: one ds_read_b64 feeds 4 k-tiles.
// ---------------------------------------------------------------------------

typedef __attribute__((ext_vector_type(8)))  short  short8;    // bf16x8 MFMA frag
typedef __attribute__((ext_vector_type(8)))  unsigned short ushort8;
typedef __attribute__((ext_vector_type(4)))  float  float4v;
typedef __attribute__((ext_vector_type(16))) float  float16v;
typedef __attribute__((ext_vector_type(4)))  unsigned int uint4v;

#define M_DIM 8192
#define I_DIM 1024
#define O_DIM 1024
#define K_DIM 8192   // I_DIM * 8
#define BM 256       // block m (4 waves x 64)
#define BN 128       // block n
#define BK 64        // 8 i-values per K-step
#define KSPLIT 2
#define KHALF (K_DIM / KSPLIT)
#define NSTEP (KHALF / BK)   // 64

// round-to-nearest-even fp32 -> bf16 bits (prep kernel)
__device__ __forceinline__ unsigned short f2bf(float f) {
    unsigned int u = __float_as_uint(f);
    u += 0x7FFFu + ((u >> 16) & 1u);
    return (unsigned short)(u >> 16);
}

// ---- merged prep: zero out, T (tanh, permuted), Bt (coeff transpose) ----
// T[b][group g] holds 8 u16 in order [i0,i2,i4,i6, i1,i3,i5,i7] (i = g*8+..):
// a ds_read_b64 at byte offset h*8 yields {t(h), t(2+h), t(4+h), t(6+h)}.
// Bt[o][i*8+d] = bf16(coeffs[i][o][d]).
__global__ __launch_bounds__(256) void prep_kernel(const float* __restrict__ x,
                                                   const float* __restrict__ c,
                                                   unsigned short* __restrict__ T,
                                                   unsigned short* __restrict__ Bt,
                                                   float* __restrict__ outz) {
    int bid = blockIdx.x;
    const int zPart = (M_DIM * O_DIM) / (4 * 256);   // 8192 blocks: zero d_out
    const int tPart = (M_DIM * I_DIM) / (8 * 256);   // 4096 blocks: tanh
    if (bid < zPart) {
        int idx = (bid * 256 + threadIdx.x) * 4;
        const float4v z = {0.f, 0.f, 0.f, 0.f};
        *(float4v*)(outz + idx) = z;
    } else if (bid < zPart + tPart) {
        int idx = ((bid - zPart) * 256 + threadIdx.x) * 8;
        float4v v0 = *(const float4v*)(x + idx);
        float4v v1 = *(const float4v*)(x + idx + 4);
        unsigned short t[8];
        t[0] = f2bf(tanhf(v0[0])); t[1] = f2bf(tanhf(v0[1]));
        t[2] = f2bf(tanhf(v0[2])); t[3] = f2bf(tanhf(v0[3]));
        t[4] = f2bf(tanhf(v1[0])); t[5] = f2bf(tanhf(v1[1]));
        t[6] = f2bf(tanhf(v1[2])); t[7] = f2bf(tanhf(v1[3]));
        ushort8 o;
        #pragma unroll
        for (int p = 0; p < 4; ++p) { o[p] = t[2 * p]; o[4 + p] = t[2 * p + 1]; }
        *(ushort8*)(T + idx) = o;
    } else {
        int idx = (bid - zPart - tPart) * 256 + threadIdx.x; // one (i,o)/thread
        int i = idx >> 10;
        int o = idx & 1023;
        const float* src = c + (size_t)i * 8192 + o * 8;
        float4v lo = *(const float4v*)(src);
        float4v hi = *(const float4v*)(src + 4);
        ushort8 v;
        v[0] = f2bf(lo[0]); v[1] = f2bf(lo[1]); v[2] = f2bf(lo[2]); v[3] = f2bf(lo[3]);
        v[4] = f2bf(hi[0]); v[5] = f2bf(hi[1]); v[6] = f2bf(hi[2]); v[7] = f2bf(hi[3]);
        *(ushort8*)(Bt + (size_t)o * K_DIM + i * 8) = v;
    }
}

// Lucas A-fragment {2, t, L2..L7} packed bf16x8 from bf16 t-bits tb (low 16).
__device__ __forceinline__ short8 lucas_frag(unsigned int tb) {
    const float t = __uint_as_float(tb << 16);
    const float L2v = fmaf(t, t, 2.0f);
    const float L3v = fmaf(t, L2v, t);
    const float L4v = fmaf(t, L3v, L2v);
    const float L5v = fmaf(t, L4v, L3v);
    const float L6v = fmaf(t, L5v, L4v);
    const float L7v = fmaf(t, L6v, L5v);
    union { uint4v u; short8 s; } r;
#if __has_builtin(__builtin_amdgcn_cvt_pk_bf16_f32)
    {
        auto p0 = __builtin_amdgcn_cvt_pk_bf16_f32(2.0f, t);
        auto p1 = __builtin_amdgcn_cvt_pk_bf16_f32(L2v, L3v);
        auto p2 = __builtin_amdgcn_cvt_pk_bf16_f32(L4v, L5v);
        auto p3 = __builtin_amdgcn_cvt_pk_bf16_f32(L6v, L7v);
        __builtin_memcpy(&r.u[0], &p0, 4);
        __builtin_memcpy(&r.u[1], &p1, 4);
        __builtin_memcpy(&r.u[2], &p2, 4);
        __builtin_memcpy(&r.u[3], &p3, 4);
    }
#else
    {
        r.u[0] = 0x4000u | (tb << 16);
        r.u[1] = __builtin_amdgcn_perm(__float_as_uint(L3v), __float_as_uint(L2v), 0x07060302);
        r.u[2] = __builtin_amdgcn_perm(__float_as_uint(L5v), __float_as_uint(L4v), 0x07060302);
        r.u[3] = __builtin_amdgcn_perm(__float_as_uint(L7v), __float_as_uint(L6v), 0x07060302);
    }
#endif
    return r.s;
}

// ---- fused GEMM (32x32x16): out[m][n] += sum_{k half} A[m][k] * Bt[n][k] ----
__global__ __launch_bounds__(256, 2) void gemm_kernel(const unsigned short* __restrict__ T,
                                                      const unsigned short* __restrict__ Bt,
                                                      float* __restrict__ out) {
    __shared__ unsigned short Bs[2][BN * BK];   // 32 KB, XOR-swizzled, dbuf
    __shared__ unsigned short Ts[2][BM * 8];    // 8 KB, dbuf (permuted 8-groups)

    const int tid  = threadIdx.x;
    const int lane = tid & 63;
    const int wave = tid >> 6;
    const int n0 = blockIdx.x * BN;        // x = n-panel (8): XCD = linear%8 = x
    const int m0 = blockIdx.y * BM;        // y = m (32)
    const int k0 = blockIdx.z * KHALF;     // z = K half (2)

    const int l32 = lane & 31;             // 32x32 MFMA: m/n index
    const int h   = lane >> 5;             // k-half selector
    const int wml = wave * 64;             // wave's m offset within block

    const int srow   = lane >> 3;          // staging: 0..7
    const int il     = lane & 7;
    const int gchunk = il ^ srow;          // XOR-swizzled global 16B chunk

    float16v acc[2][4];
    #pragma unroll
    for (int a = 0; a < 2; ++a)
        #pragma unroll
        for (int b = 0; b < 4; ++b)
            #pragma unroll
            for (int e = 0; e < 16; ++e) acc[a][b][e] = 0.f;

    // stage one K-step: B 4 insts/wave (8 rows each), T 1 inst/wave (64 rows)
    auto stage = [&](int buf, int kt) {
        #pragma unroll
        for (int r = 0; r < 4; ++r) {
            const int rowb = r * 32 + wave * 8;
            const unsigned short* gB = Bt + (size_t)(n0 + rowb + srow) * K_DIM + kt + gchunk * 8;
            __builtin_amdgcn_global_load_lds(
                (const __attribute__((address_space(1))) unsigned int*)gB,
                (__attribute__((address_space(3))) unsigned int*)&Bs[buf][rowb * BK], 16, 0, 0);
        }
        const unsigned short* gT = T + (size_t)(m0 + wml + lane) * I_DIM + kt / 8;
        __builtin_amdgcn_global_load_lds(
            (const __attribute__((address_space(1))) unsigned int*)gT,
            (__attribute__((address_space(3))) unsigned int*)&Ts[buf][wml * 8], 16, 0, 0);
    };

    stage(0, k0);
    __syncthreads();

    int cur = 0;
    for (int s = 0; s < NSTEP; ++s) {
        const int nxt = cur ^ 1;
        if (s + 1 < NSTEP) stage(nxt, k0 + (s + 1) * BK);

        // t-words: one b64 per m-tile = {t(h), t(2+h), t(4+h), t(6+h)}
        unsigned long long tw[2];
        #pragma unroll
        for (int tt = 0; tt < 2; ++tt)
            tw[tt] = *(const unsigned long long*)&Ts[cur][(wml + tt * 32 + l32) * 8 + h * 4];

        #pragma unroll
        for (int kk = 0; kk < 4; ++kk) {   // K-tile of 16 within BK=64
            short8 bfr[4];
            #pragma unroll
            for (int tn = 0; tn < 4; ++tn) {
                const int brow = tn * 32 + l32;
                bfr[tn] = *(const short8*)&Bs[cur][brow * BK + (((kk * 2 + h) ^ (brow & 7)) * 8)];
            }
            #pragma unroll
            for (int tt = 0; tt < 2; ++tt) {
                const short8 af = lucas_frag((unsigned int)((tw[tt] >> (16 * kk)) & 0xffffu));
                #pragma unroll
                for (int tn = 0; tn < 4; ++tn)
                    acc[tt][tn] = __builtin_amdgcn_mfma_f32_32x32x16_bf16(
                        af, bfr[tn], acc[tt][tn], 0, 0, 0);
            }
        }

        __syncthreads();   // drains prefetch + protects Bs/Ts swap
        cur = nxt;
    }

    // epilogue: 32x32 C/D: col = lane&31, row = (reg&3) + 8*(reg>>2) + 4*(lane>>5)
    #pragma unroll
    for (int tt = 0; tt < 2; ++tt) {
        #pragma unroll
        for (int tn = 0; tn < 4; ++tn) {
            const int col = n0 + tn * 32 + l32;
            #pragma unroll
            for (int reg = 0; reg < 16; ++reg) {
                const int row = m0 + wml + tt * 32 + (reg & 3) + 8 * (reg >> 2) + 4 * h;
                atomicAdd(&out[(size_t)row * O_DIM + col], acc[tt][tn][reg]);
            }
        }
    }
}

// ---- fallback (tiny workspace): direct fp32 ----
__global__ __launch_bounds__(256) void naive_kernel(const float* __restrict__ x,
                                                    const float* __restrict__ c,
                                                    float* __restrict__ out) {
    int idx = blockIdx.x * 256 + threadIdx.x;   // one (b,o)
    int b = idx >> 10;
    int o = idx & 1023;
    const float* xb = x + (size_t)b * I_DIM;
    float acc = 0.f;
    for (int i = 0; i < I_DIM; ++i) {
        float t = tanhf(xb[i]);
        float L[8];
        L[0] = 2.0f; L[1] = t;
        #pragma unroll
        for (int d = 2; d < 8; ++d) L[d] = t * L[d - 1] + L[d - 2];
        const float* cc = c + (size_t)i * 8192 + o * 8;
        #pragma unroll
        for (int d = 0; d < 8; ++d) acc += L[d] * cc[d];
    }
    out[idx] = acc;
}

extern "C" void kernel_launch(void* const* d_in, const int* in_sizes, int n_in,
                              void* d_out, int out_size, void* d_ws, size_t ws_size,
                              hipStream_t stream) {
    const float* x      = (const float*)d_in[0];
    const float* coeffs = (const float*)d_in[1];
    float* out = (float*)d_out;

    const size_t btBytes = (size_t)O_DIM * K_DIM * sizeof(unsigned short);   // 16 MiB
    const size_t tBytes  = (size_t)M_DIM * I_DIM * sizeof(unsigned short);   // 16 MiB

    if (ws_size >= btBytes + tBytes) {
        unsigned short* Bt = (unsigned short*)d_ws;
        unsigned short* T  = (unsigned short*)((char*)d_ws + btBytes);

        const int zBlocks = (M_DIM * O_DIM) / (4 * 256);   // 8192
        const int tBlocks = (M_DIM * I_DIM) / (8 * 256);   // 4096
        const int bBlocks = (I_DIM * O_DIM) / 256;          // 4096
        prep_kernel<<<zBlocks + tBlocks + bBlocks, 256, 0, stream>>>(x, coeffs, T, Bt, out);

        dim3 grid(O_DIM / BN, M_DIM / BM, KSPLIT);   // (8, 32, 2): XCD = x
        gemm_kernel<<<grid, 256, 0, stream>>>(T, Bt, out);
    } else {
        naive_kernel<<<(M_DIM * O_DIM) / 256, 256, 0, stream>>>(x, coeffs, out);
    }
}

// Round 9
// 259.297 us; speedup vs baseline: 1.2366x; 1.0023x over previous
//
#include <hip/hip_runtime.h>
#include <hip/hip_bf16.h>

// ---------------------------------------------------------------------------
// LucasKANLayer fused: y[b,o] = sum_i sum_d L_d(tanh(x[b,i])) * C[i,o,d]
// R9: GEMM = R6 occupancy (128x128 block, 4 waves, 4 blocks/CU) with R8's
// verified mfma_f32_32x32x16_bf16 (acc 2x2x16 = 64 regs -> 4 waves/SIMD).
// Prep v2: B-transpose through LDS tiles (coalesced reads AND writes) --
// R1-R8 prep was ~105 us (uncoalesced 16B-stride-16KB stores), ideal ~25.
// ---------------------------------------------------------------------------

typedef __attribute__((ext_vector_type(8)))  short  short8;    // bf16x8 MFMA frag
typedef __attribute__((ext_vector_type(4)))  unsigned short ushort4v;
typedef __attribute__((ext_vector_type(8)))  unsigned short ushort8;
typedef __attribute__((ext_vector_type(4)))  float  float4v;
typedef __attribute__((ext_vector_type(16))) float  float16v;
typedef __attribute__((ext_vector_type(4)))  unsigned int uint4v;

#define M_DIM 8192
#define I_DIM 1024
#define O_DIM 1024
#define K_DIM 8192   // I_DIM * 8
#define BM 128       // block m (2x2 waves of 64x64)
#define BN 128       // block n
#define BK 64        // 8 i-values per K-step
#define KSPLIT 2
#define KHALF (K_DIM / KSPLIT)
#define NSTEP (KHALF / BK)   // 64

// round-to-nearest-even fp32 -> bf16 bits (prep kernel)
__device__ __forceinline__ unsigned short f2bf(float f) {
    unsigned int u = __float_as_uint(f);
    u += 0x7FFFu + ((u >> 16) & 1u);
    return (unsigned short)(u >> 16);
}

// ---- prep: zero d_out | T (tanh, permuted 8-groups) | Bt transpose via LDS ----
// T[b][group g] holds 8 u16 in order [i0,i2,i4,i6, i1,i3,i5,i7] (i = g*8+..):
// b64 read at +h*8 bytes yields {t(h), t(2+h), t(4+h), t(6+h)}  [R8-verified].
// Bt[o][i*8+d] = bf16(coeffs[i][o][d])                          [R8-verified].
__global__ __launch_bounds__(256) void prep_kernel(const float* __restrict__ x,
                                                   const float* __restrict__ c,
                                                   unsigned short* __restrict__ T,
                                                   unsigned short* __restrict__ Bt,
                                                   float* __restrict__ outz) {
    const int zPart = (M_DIM * O_DIM) / (4 * 256);   // 8192 blocks: zero d_out
    const int tPart = (M_DIM * I_DIM) / (8 * 256);   // 4096 blocks: tanh
    int bid = blockIdx.x;
    int tid = threadIdx.x;
    if (bid < zPart) {
        int idx = (bid * 256 + tid) * 4;
        const float4v z = {0.f, 0.f, 0.f, 0.f};
        *(float4v*)(outz + idx) = z;
    } else if (bid < zPart + tPart) {
        int idx = ((bid - zPart) * 256 + tid) * 8;
        float4v v0 = *(const float4v*)(x + idx);
        float4v v1 = *(const float4v*)(x + idx + 4);
        unsigned short t[8];
        t[0] = f2bf(tanhf(v0[0])); t[1] = f2bf(tanhf(v0[1]));
        t[2] = f2bf(tanhf(v0[2])); t[3] = f2bf(tanhf(v0[3]));
        t[4] = f2bf(tanhf(v1[0])); t[5] = f2bf(tanhf(v1[1]));
        t[6] = f2bf(tanhf(v1[2])); t[7] = f2bf(tanhf(v1[3]));
        ushort8 o;
        #pragma unroll
        for (int p = 0; p < 4; ++p) { o[p] = t[2 * p]; o[4 + p] = t[2 * p + 1]; }
        *(ushort8*)(T + idx) = o;
    } else {
        // ---- B transpose: tile 64 i x 32 o through LDS ----
        __shared__ unsigned short S[32][64 * 8 + 8];   // [o_local][i_local*8+d], pad 16B
        int tb = bid - zPart - tPart;                  // 0..511
        const int i0 = (tb >> 5) * 64;                 // 16 i-tiles
        const int o0 = (tb & 31) * 32;                 // 32 o-tiles
        // read phase: 16 passes; pass p: rows i0+p*4 .. +3, thread t covers
        // float4 at row (p*4 + t/64), elems (t%64)*4 of the 256-float o-slice.
        #pragma unroll 4
        for (int p = 0; p < 16; ++p) {
            const int il = p * 4 + (tid >> 6);
            const int e  = (tid & 63) * 4;             // 0..252, d = e%8 in {0,4}
            const float* src = c + (size_t)(i0 + il) * 8192 + o0 * 8 + e;
            float4v v = *(const float4v*)src;
            ushort4v u;
            u[0] = f2bf(v[0]); u[1] = f2bf(v[1]); u[2] = f2bf(v[2]); u[3] = f2bf(v[3]);
            *(ushort4v*)&S[e >> 3][il * 8 + (e & 7)] = u;
        }
        __syncthreads();
        // write phase: 16 passes; pass q: o-rows o0+q*2 .. +1, thread t writes
        // 8B chunk (t%128) of the 1KB row.
        #pragma unroll 4
        for (int q = 0; q < 16; ++q) {
            const int ol = q * 2 + (tid >> 7);
            const int ch = (tid & 127) * 4;            // u16 chunk offset
            ushort4v u = *(const ushort4v*)&S[ol][ch];
            *(ushort4v*)(Bt + (size_t)(o0 + ol) * K_DIM + i0 * 8 + ch) = u;
        }
    }
}

// Lucas A-fragment {2, t, L2..L7} packed bf16x8 from bf16 t-bits tb (low 16).
__device__ __forceinline__ short8 lucas_frag(unsigned int tb) {
    const float t = __uint_as_float(tb << 16);
    const float L2v = fmaf(t, t, 2.0f);
    const float L3v = fmaf(t, L2v, t);
    const float L4v = fmaf(t, L3v, L2v);
    const float L5v = fmaf(t, L4v, L3v);
    const float L6v = fmaf(t, L5v, L4v);
    const float L7v = fmaf(t, L6v, L5v);
    union { uint4v u; short8 s; } r;
#if __has_builtin(__builtin_amdgcn_cvt_pk_bf16_f32)
    {
        auto p0 = __builtin_amdgcn_cvt_pk_bf16_f32(2.0f, t);
        auto p1 = __builtin_amdgcn_cvt_pk_bf16_f32(L2v, L3v);
        auto p2 = __builtin_amdgcn_cvt_pk_bf16_f32(L4v, L5v);
        auto p3 = __builtin_amdgcn_cvt_pk_bf16_f32(L6v, L7v);
        __builtin_memcpy(&r.u[0], &p0, 4);
        __builtin_memcpy(&r.u[1], &p1, 4);
        __builtin_memcpy(&r.u[2], &p2, 4);
        __builtin_memcpy(&r.u[3], &p3, 4);
    }
#else
    {
        r.u[0] = 0x4000u | (tb << 16);
        r.u[1] = __builtin_amdgcn_perm(__float_as_uint(L3v), __float_as_uint(L2v), 0x07060302);
        r.u[2] = __builtin_amdgcn_perm(__float_as_uint(L5v), __float_as_uint(L4v), 0x07060302);
        r.u[3] = __builtin_amdgcn_perm(__float_as_uint(L7v), __float_as_uint(L6v), 0x07060302);
    }
#endif
    return r.s;
}

// ---- fused GEMM (32x32x16): out[m][n] += sum_{k half} A[m][k] * Bt[n][k] ----
__global__ __launch_bounds__(256, 4) void gemm_kernel(const unsigned short* __restrict__ T,
                                                      const unsigned short* __restrict__ Bt,
                                                      float* __restrict__ out) {
    __shared__ unsigned short Bs[2][BN * BK];   // 32 KB, XOR-swizzled, dbuf
    __shared__ unsigned short Ts[2][BM * 8];    // 4 KB, dbuf (permuted 8-groups)

    const int tid  = threadIdx.x;
    const int lane = tid & 63;
    const int wave = tid >> 6;
    const int n0 = blockIdx.x * BN;        // x = n-panel (8): XCD = linear%8 = x
    const int m0 = blockIdx.y * BM;        // y = m (64)
    const int k0 = blockIdx.z * KHALF;     // z = K half (2)

    const int wm0 = (wave >> 1) * 64;      // wave tile 64m x 64n
    const int wn0 = (wave & 1) * 64;
    const int l32 = lane & 31;             // 32x32 MFMA: m/n index
    const int h   = lane >> 5;             // k-half selector

    const int srow   = lane >> 3;          // staging: 0..7
    const int il     = lane & 7;
    const int gchunk = il ^ srow;          // XOR-swizzled global 16B chunk

    float16v acc[2][2];
    #pragma unroll
    for (int a = 0; a < 2; ++a)
        #pragma unroll
        for (int b = 0; b < 2; ++b)
            #pragma unroll
            for (int e = 0; e < 16; ++e) acc[a][b][e] = 0.f;

    // stage one K-step: B 4 insts/wave (8 rows each, 128 total), T wave<2
    auto stage = [&](int buf, int kt) {
        #pragma unroll
        for (int r = 0; r < 4; ++r) {
            const int rowb = r * 32 + wave * 8;
            const unsigned short* gB = Bt + (size_t)(n0 + rowb + srow) * K_DIM + kt + gchunk * 8;
            __builtin_amdgcn_global_load_lds(
                (const __attribute__((address_space(1))) unsigned int*)gB,
                (__attribute__((address_space(3))) unsigned int*)&Bs[buf][rowb * BK], 16, 0, 0);
        }
        if (wave < 2) {
            const unsigned short* gT = T + (size_t)(m0 + wave * 64 + lane) * I_DIM + kt / 8;
            __builtin_amdgcn_global_load_lds(
                (const __attribute__((address_space(1))) unsigned int*)gT,
                (__attribute__((address_space(3))) unsigned int*)&Ts[buf][wave * 64 * 8], 16, 0, 0);
        }
    };

    stage(0, k0);
    __syncthreads();

    int cur = 0;
    for (int s = 0; s < NSTEP; ++s) {
        const int nxt = cur ^ 1;
        if (s + 1 < NSTEP) stage(nxt, k0 + (s + 1) * BK);

        // t-words: one b64 per m-tile = {t(h), t(2+h), t(4+h), t(6+h)}
        unsigned long long tw[2];
        #pragma unroll
        for (int tt = 0; tt < 2; ++tt)
            tw[tt] = *(const unsigned long long*)&Ts[cur][(wm0 + tt * 32 + l32) * 8 + h * 4];

        #pragma unroll
        for (int kk = 0; kk < 4; ++kk) {   // K-tile of 16 within BK=64
            short8 bfr[2];
            #pragma unroll
            for (int tn = 0; tn < 2; ++tn) {
                const int brow = wn0 + tn * 32 + l32;
                bfr[tn] = *(const short8*)&Bs[cur][brow * BK + (((kk * 2 + h) ^ (brow & 7)) * 8)];
            }
            #pragma unroll
            for (int tt = 0; tt < 2; ++tt) {
                const short8 af = lucas_frag((unsigned int)((tw[tt] >> (16 * kk)) & 0xffffu));
                #pragma unroll
                for (int tn = 0; tn < 2; ++tn)
                    acc[tt][tn] = __builtin_amdgcn_mfma_f32_32x32x16_bf16(
                        af, bfr[tn], acc[tt][tn], 0, 0, 0);
            }
        }

        __syncthreads();   // drains prefetch + protects Bs/Ts swap
        cur = nxt;
    }

    // epilogue (R8-verified): col = lane&31, row = (reg&3) + 8*(reg>>2) + 4*h
    #pragma unroll
    for (int tt = 0; tt < 2; ++tt) {
        #pragma unroll
        for (int tn = 0; tn < 2; ++tn) {
            const int col = n0 + wn0 + tn * 32 + l32;
            #pragma unroll
            for (int reg = 0; reg < 16; ++reg) {
                const int row = m0 + wm0 + tt * 32 + (reg & 3) + 8 * (reg >> 2) + 4 * h;
                atomicAdd(&out[(size_t)row * O_DIM + col], acc[tt][tn][reg]);
            }
        }
    }
}

// ---- fallback (tiny workspace): direct fp32 ----
__global__ __launch_bounds__(256) void naive_kernel(const float* __restrict__ x,
                                                    const float* __restrict__ c,
                                                    float* __restrict__ out) {
    int idx = blockIdx.x * 256 + threadIdx.x;   // one (b,o)
    int b = idx >> 10;
    int o = idx & 1023;
    const float* xb = x + (size_t)b * I_DIM;
    float acc = 0.f;
    for (int i = 0; i < I_DIM; ++i) {
        float t = tanhf(xb[i]);
        float L[8];
        L[0] = 2.0f; L[1] = t;
        #pragma unroll
        for (int d = 2; d < 8; ++d) L[d] = t * L[d - 1] + L[d - 2];
        const float* cc = c + (size_t)i * 8192 + o * 8;
        #pragma unroll
        for (int d = 0; d < 8; ++d) acc += L[d] * cc[d];
    }
    out[idx] = acc;
}

extern "C" void kernel_launch(void* const* d_in, const int* in_sizes, int n_in,
                              void* d_out, int out_size, void* d_ws, size_t ws_size,
                              hipStream_t stream) {
    const float* x      = (const float*)d_in[0];
    const float* coeffs = (const float*)d_in[1];
    float* out = (float*)d_out;

    const size_t btBytes = (size_t)O_DIM * K_DIM * sizeof(unsigned short);   // 16 MiB
    const size_t tBytes  = (size_t)M_DIM * I_DIM * sizeof(unsigned short);   // 16 MiB

    if (ws_size >= btBytes + tBytes) {
        unsigned short* Bt = (unsigned short*)d_ws;
        unsigned short* T  = (unsigned short*)((char*)d_ws + btBytes);

        const int zBlocks = (M_DIM * O_DIM) / (4 * 256);   // 8192
        const int tBlocks = (M_DIM * I_DIM) / (8 * 256);   // 4096
        const int xBlocks = (I_DIM / 64) * (I_DIM / 32);   // 512 transpose tiles
        prep_kernel<<<zBlocks + tBlocks + xBlocks, 256, 0, stream>>>(x, coeffs, T, Bt, out);

        dim3 grid(O_DIM / BN, M_DIM / BM, KSPLIT);   // (8, 64, 2): XCD = x
        gemm_kernel<<<grid, 256, 0, stream>>>(T, Bt, out);
    } else {
        naive_kernel<<<(M_DIM * O_DIM) / 256, 256, 0, stream>>>(x, coeffs, out);
    }
}

// Round 11
// 247.841 us; speedup vs baseline: 1.2937x; 1.0462x over previous
//
#include <hip/hip_runtime.h>
#include <hip/hip_bf16.h>

// ---------------------------------------------------------------------------
// LucasKANLayer fused: y[b,o] = sum_i sum_d L_d(tanh(x[b,i])) * C[i,o,d]
// R11 = R6 structure (verified: dbuf global_load_lds staging, XOR swizzle,
// 1 barrier/step, KSPLIT=2, 4 blocks/CU, XCD-pinned B-panels) with wave
// tile 32m x 128n: Lucas frags/wave/step 8 -> 4 (each A-frag feeds 8 MFMAs),
// acc still 64 regs -> 4 waves/SIMD kept. R6's SIMD issue port was saturated
// MFMA(43%)+VALU(47%); this halves the VALU term.
// (R10's barrier-free producer/consumer FAILED correctness - reverted.)
// ---------------------------------------------------------------------------

typedef __attribute__((ext_vector_type(8)))  short  short8;    // bf16x8 MFMA frag
typedef __attribute__((ext_vector_type(4)))  unsigned short ushort4v;
typedef __attribute__((ext_vector_type(8)))  unsigned short ushort8;
typedef __attribute__((ext_vector_type(4)))  float  float4v;
typedef __attribute__((ext_vector_type(4)))  unsigned int uint4v;

#define M_DIM 8192
#define I_DIM 1024
#define O_DIM 1024
#define K_DIM 8192   // I_DIM * 8
#define BM 128
#define BN 128
#define BK 64        // 8 i-values per K-step
#define KSPLIT 2
#define KHALF (K_DIM / KSPLIT)
#define NSTEP (KHALF / BK)   // 64

// round-to-nearest-even fp32 -> bf16 bits (prep kernel)
__device__ __forceinline__ unsigned short f2bf(float f) {
    unsigned int u = __float_as_uint(f);
    u += 0x7FFFu + ((u >> 16) & 1u);
    return (unsigned short)(u >> 16);
}

// ---- prep: zero d_out | T (tanh, permuted 8-groups) | Bt transpose via LDS ----
// T[b][group g]: slot 2p = t(i=g*8+p), slot 2p+1 = t(i=g*8+p+4): b32 read at
// u16-offset quad*2 gives {lo=t(quad), hi=t(quad+4)}       [R6-verified].
// Bt[o][i*8+d] = bf16(coeffs[i][o][d])                     [R9-verified].
__global__ __launch_bounds__(256) void prep_kernel(const float* __restrict__ x,
                                                   const float* __restrict__ c,
                                                   unsigned short* __restrict__ T,
                                                   unsigned short* __restrict__ Bt,
                                                   float* __restrict__ outz) {
    const int zPart = (M_DIM * O_DIM) / (4 * 256);   // 8192 blocks: zero d_out
    const int tPart = (M_DIM * I_DIM) / (8 * 256);   // 4096 blocks: tanh
    int bid = blockIdx.x;
    int tid = threadIdx.x;
    if (bid < zPart) {
        int idx = (bid * 256 + tid) * 4;
        const float4v z = {0.f, 0.f, 0.f, 0.f};
        *(float4v*)(outz + idx) = z;
    } else if (bid < zPart + tPart) {
        int idx = ((bid - zPart) * 256 + tid) * 8;
        float4v v0 = *(const float4v*)(x + idx);
        float4v v1 = *(const float4v*)(x + idx + 4);
        unsigned short t[8];
        t[0] = f2bf(tanhf(v0[0])); t[1] = f2bf(tanhf(v0[1]));
        t[2] = f2bf(tanhf(v0[2])); t[3] = f2bf(tanhf(v0[3]));
        t[4] = f2bf(tanhf(v1[0])); t[5] = f2bf(tanhf(v1[1]));
        t[6] = f2bf(tanhf(v1[2])); t[7] = f2bf(tanhf(v1[3]));
        ushort8 o;
        #pragma unroll
        for (int p = 0; p < 4; ++p) { o[2 * p] = t[p]; o[2 * p + 1] = t[p + 4]; }
        *(ushort8*)(T + idx) = o;
    } else {
        // B transpose: tile 64 i x 32 o through LDS (coalesced R+W)
        __shared__ unsigned short S[32][64 * 8 + 8];
        int tb = bid - zPart - tPart;                  // 0..511
        const int i0 = (tb >> 5) * 64;
        const int o0 = (tb & 31) * 32;
        #pragma unroll 4
        for (int p = 0; p < 16; ++p) {
            const int il = p * 4 + (tid >> 6);
            const int e  = (tid & 63) * 4;
            const float* src = c + (size_t)(i0 + il) * 8192 + o0 * 8 + e;
            float4v v = *(const float4v*)src;
            ushort4v u;
            u[0] = f2bf(v[0]); u[1] = f2bf(v[1]); u[2] = f2bf(v[2]); u[3] = f2bf(v[3]);
            *(ushort4v*)&S[e >> 3][il * 8 + (e & 7)] = u;
        }
        __syncthreads();
        #pragma unroll 4
        for (int q = 0; q < 16; ++q) {
            const int ol = q * 2 + (tid >> 7);
            const int ch = (tid & 127) * 4;
            ushort4v u = *(const ushort4v*)&S[ol][ch];
            *(ushort4v*)(Bt + (size_t)(o0 + ol) * K_DIM + i0 * 8 + ch) = u;
        }
    }
}

// Lucas A-fragment {2, t, L2..L7} packed bf16x8 from bf16 t-bits tb (low 16).
__device__ __forceinline__ short8 lucas_frag(unsigned int tb) {
    const float t = __uint_as_float(tb << 16);
    const float L2v = fmaf(t, t, 2.0f);
    const float L3v = fmaf(t, L2v, t);
    const float L4v = fmaf(t, L3v, L2v);
    const float L5v = fmaf(t, L4v, L3v);
    const float L6v = fmaf(t, L5v, L4v);
    const float L7v = fmaf(t, L6v, L5v);
    union { uint4v u; short8 s; } r;
#if __has_builtin(__builtin_amdgcn_cvt_pk_bf16_f32)
    {
        auto p0 = __builtin_amdgcn_cvt_pk_bf16_f32(2.0f, t);
        auto p1 = __builtin_amdgcn_cvt_pk_bf16_f32(L2v, L3v);
        auto p2 = __builtin_amdgcn_cvt_pk_bf16_f32(L4v, L5v);
        auto p3 = __builtin_amdgcn_cvt_pk_bf16_f32(L6v, L7v);
        __builtin_memcpy(&r.u[0], &p0, 4);
        __builtin_memcpy(&r.u[1], &p1, 4);
        __builtin_memcpy(&r.u[2], &p2, 4);
        __builtin_memcpy(&r.u[3], &p3, 4);
    }
#else
    {
        r.u[0] = 0x4000u | (tb << 16);
        r.u[1] = __builtin_amdgcn_perm(__float_as_uint(L3v), __float_as_uint(L2v), 0x07060302);
        r.u[2] = __builtin_amdgcn_perm(__float_as_uint(L5v), __float_as_uint(L4v), 0x07060302);
        r.u[3] = __builtin_amdgcn_perm(__float_as_uint(L7v), __float_as_uint(L6v), 0x07060302);
    }
#endif
    return r.s;
}

// ---- fused GEMM: out[m][n] += sum_{k half} A[m][k] * Bt[n][k] ----
// wave tile 32m x 128n: wave w owns m rows [w*32, w*32+32), all 128 n.
__global__ __launch_bounds__(256, 4) void gemm_kernel(const unsigned short* __restrict__ T,
                                                      const unsigned short* __restrict__ Bt,
                                                      float* __restrict__ out) {
    __shared__ unsigned short Bs[2][BN * BK];   // 32 KB, XOR-swizzled, dbuf
    __shared__ unsigned short Ts[2][BM * 8];    // 4 KB, dbuf (permuted 8-groups)

    const int tid  = threadIdx.x;
    const int lane = tid & 63;
    const int wave = tid >> 6;
    const int n0 = blockIdx.x * BN;        // x = n-panel (8): XCD = linear%8 = x
    const int m0 = blockIdx.y * BM;        // y = m (64)
    const int k0 = blockIdx.z * KHALF;     // z = K half (2)

    const int wm0  = wave * 32;            // wave tile 32m x 128n
    const int l16  = lane & 15;
    const int quad = lane >> 4;

    const int srow   = lane >> 3;          // staging: 0..7
    const int il     = lane & 7;
    const int gchunk = il ^ srow;          // XOR-swizzled global 16B chunk

    float4v acc[2][8];
    const float4v zero = {0.f, 0.f, 0.f, 0.f};
    #pragma unroll
    for (int a = 0; a < 2; ++a)
        #pragma unroll
        for (int b = 0; b < 8; ++b) acc[a][b] = zero;

    // stage one K-step: B 4 insts/wave (8 rows each, 128 total), T wave<2
    auto stage = [&](int buf, int kt) {
        #pragma unroll
        for (int r = 0; r < 4; ++r) {
            const int rowb = r * 32 + wave * 8;
            const unsigned short* gB = Bt + (size_t)(n0 + rowb + srow) * K_DIM + kt + gchunk * 8;
            __builtin_amdgcn_global_load_lds(
                (const __attribute__((address_space(1))) unsigned int*)gB,
                (__attribute__((address_space(3))) unsigned int*)&Bs[buf][rowb * BK], 16, 0, 0);
        }
        if (wave < 2) {
            const unsigned short* gT = T + (size_t)(m0 + wave * 64 + lane) * I_DIM + kt / 8;
            __builtin_amdgcn_global_load_lds(
                (const __attribute__((address_space(1))) unsigned int*)gT,
                (__attribute__((address_space(3))) unsigned int*)&Ts[buf][wave * 64 * 8], 16, 0, 0);
        }
    };

    stage(0, k0);
    __syncthreads();

    int cur = 0;
    for (int s = 0; s < NSTEP; ++s) {
        const int nxt = cur ^ 1;
        if (s + 1 < NSTEP) stage(nxt, k0 + (s + 1) * BK);

        // t-words: one b32 per m-tile {lo=t(quad)->k2=0, hi=t(quad+4)->k2=1}
        unsigned int tw[2];
        #pragma unroll
        for (int tt = 0; tt < 2; ++tt)
            tw[tt] = *(const unsigned int*)&Ts[cur][(wm0 + tt * 16 + l16) * 8 + quad * 2];

        #pragma unroll
        for (int k2 = 0; k2 < 2; ++k2) {
            short8 af[2];
            af[0] = lucas_frag(k2 ? (tw[0] >> 16) : (tw[0] & 0xffffu));
            af[1] = lucas_frag(k2 ? (tw[1] >> 16) : (tw[1] & 0xffffu));
            #pragma unroll
            for (int g = 0; g < 2; ++g) {          // n-halves: <=4 live b-frags
                short8 bfr[4];
                #pragma unroll
                for (int j = 0; j < 4; ++j) {
                    const int brow = (g * 4 + j) * 16 + l16;
                    bfr[j] = *(const short8*)&Bs[cur][brow * BK + (((k2 * 4 + quad) ^ (l16 & 7)) * 8)];
                }
                #pragma unroll
                for (int tt = 0; tt < 2; ++tt)
                    #pragma unroll
                    for (int j = 0; j < 4; ++j)
                        acc[tt][g * 4 + j] = __builtin_amdgcn_mfma_f32_16x16x32_bf16(
                            af[tt], bfr[j], acc[tt][g * 4 + j], 0, 0, 0);
            }
        }

        __syncthreads();   // drains prefetch + protects Bs/Ts swap
        cur = nxt;
    }

    // epilogue: D[row=(lane>>4)*4+r][col=lane&15] (verified R1-R9)
    #pragma unroll
    for (int tt = 0; tt < 2; ++tt) {
        #pragma unroll
        for (int tn = 0; tn < 8; ++tn) {
            const int col = n0 + tn * 16 + l16;
            #pragma unroll
            for (int r = 0; r < 4; ++r) {
                const int row = m0 + wm0 + tt * 16 + quad * 4 + r;
                atomicAdd(&out[(size_t)row * O_DIM + col], acc[tt][tn][r]);
            }
        }
    }
}

// ---- fallback (tiny workspace): direct fp32 ----
__global__ __launch_bounds__(256) void naive_kernel(const float* __restrict__ x,
                                                    const float* __restrict__ c,
                                                    float* __restrict__ out) {
    int idx = blockIdx.x * 256 + threadIdx.x;   // one (b,o)
    int b = idx >> 10;
    int o = idx & 1023;
    const float* xb = x + (size_t)b * I_DIM;
    float acc = 0.f;
    for (int i = 0; i < I_DIM; ++i) {
        float t = tanhf(xb[i]);
        float L[8];
        L[0] = 2.0f; L[1] = t;
        #pragma unroll
        for (int d = 2; d < 8; ++d) L[d] = t * L[d - 1] + L[d - 2];
        const float* cc = c + (size_t)i * 8192 + o * 8;
        #pragma unroll
        for (int d = 0; d < 8; ++d) acc += L[d] * cc[d];
    }
    out[idx] = acc;
}

extern "C" void kernel_launch(void* const* d_in, const int* in_sizes, int n_in,
                              void* d_out, int out_size, void* d_ws, size_t ws_size,
                              hipStream_t stream) {
    const float* x      = (const float*)d_in[0];
    const float* coeffs = (const float*)d_in[1];
    float* out = (float*)d_out;

    const size_t btBytes = (size_t)O_DIM * K_DIM * sizeof(unsigned short);   // 16 MiB
    const size_t tBytes  = (size_t)M_DIM * I_DIM * sizeof(unsigned short);   // 16 MiB

    if (ws_size >= btBytes + tBytes) {
        unsigned short* Bt = (unsigned short*)d_ws;
        unsigned short* T  = (unsigned short*)((char*)d_ws + btBytes);

        const int zBlocks = (M_DIM * O_DIM) / (4 * 256);   // 8192
        const int tBlocks = (M_DIM * I_DIM) / (8 * 256);   // 4096
        const int xBlocks = (I_DIM / 64) * (I_DIM / 32);   // 512 transpose tiles
        prep_kernel<<<zBlocks + tBlocks + xBlocks, 256, 0, stream>>>(x, coeffs, T, Bt, out);

        dim3 grid(O_DIM / BN, M_DIM / BM, KSPLIT);   // (8, 64, 2): XCD = x
        gemm_kernel<<<grid, 256, 0, stream>>>(T, Bt, out);
    } else {
        naive_kernel<<<(M_DIM * O_DIM) / 256, 256, 0, stream>>>(x, coeffs, out);
    }
}